// Round 14
// baseline (651.459 us; speedup 1.0000x reference)
//
#include <hip/hip_runtime.h>
#include <math.h>

#define NND 20000
#define NE  320000
#define NF  128
#define EPS 1e-5f
#define TE  64             // edges per tile (passB)
#define NT  256
#define NTILES (NE / TE)   // 5000
#define NGRP (NE / 4)      // 80000 edge groups of 4 (edge_pass)
#define EGRID 1024         // r13 sweep: 768->1024 (4/CU). 768 measured 57.3us at
                           // 24.9% occ; 1536 (r7, pre-DPP kernel) was worse --
                           // prologue amortization. 1024 is the untested midpoint.
#define XST 136            // LDS stride for 128-wide bf16 tiles (shorts)
#define BST 40             // LDS stride for B slab rows (shorts)

typedef short short8 __attribute__((ext_vector_type(8)));
typedef float float4v __attribute__((ext_vector_type(4)));

__device__ __forceinline__ float psif(float z) {
    // sign(z)*log1p(|z|); __logf(1+|z|) error <=1e-5 through w6 (budget 3.9e-3)
    return copysignf(__logf(1.f + fabsf(z)), z);
}
__device__ __forceinline__ float sigm(float z) {
    return 1.f / (1.f + expf(-z));
}
__device__ __forceinline__ short f2bf(float f) {
    union { float f; unsigned u; } v; v.f = f;
    unsigned r = v.u + 0x7fffu + ((v.u >> 16) & 1u);
    return (short)(r >> 16);
}
__device__ __forceinline__ float bf2f(short u) {
    union { unsigned u; float f; } v; v.u = ((unsigned)(unsigned short)u) << 16;
    return v.f;
}
__device__ __forceinline__ float clipf(float v) {
    return fminf(fmaxf(v, -100.f), 100.f);
}

// rotate-reduce within each 16-lane DPP row: after steps 1,2,4,8 every lane
// holds the row sum. VALU-pipe (no ds_swizzle / lgkmcnt serial chain).
template<int N>
__device__ __forceinline__ float ror16_add(float v) {
    int r = __builtin_amdgcn_update_dpp(
        0, __float_as_int(v), 0x120 + N /*row_ror:N*/, 0xF, 0xF, false);
    return v + __int_as_float(r);
}
__device__ __forceinline__ float rowsum16(float v) {
    v = ror16_add<1>(v);
    v = ror16_add<2>(v);
    v = ror16_add<4>(v);
    v = ror16_add<8>(v);
    return v;
}

// stage one K=32 slab of Wt [128 rows n][wstride k] (bf16) into LDS bt[128][BST]
__device__ __forceinline__ void stage_b(const unsigned short* __restrict__ wsrc, int wstride,
                                        int ks, short* bt, int t) {
    #pragma unroll
    for (int rr = 0; rr < 2; ++rr) {
        int c = t + rr * 256;          // 512 chunks of 8 bf16
        int n = c >> 2, h = c & 3;
        short8 v = *(const short8*)(wsrc + (size_t)n * wstride + ks * 32 + h * 8);
        *(short8*)(bt + n * BST + h * 8) = v;
    }
}

// B-slab staging split for double-buffered loops (passB).
// NOTE (r10 lesson): do NOT replace LDS-dbuf B staging with per-wave global
// fragment loads — in-loop VMEM latency + same-line L2 contention made passB
// 64 -> 89.6us despite higher occupancy and fewer bank conflicts.
__device__ __forceinline__ void ldreg_b(const unsigned short* __restrict__ w, int wstride,
                                        int ks, int t, short8* r) {
    #pragma unroll
    for (int rr = 0; rr < 2; ++rr) {
        int c = t + rr * 256;
        int n = c >> 2, h = c & 3;
        r[rr] = *(const short8*)(w + (size_t)n * wstride + ks * 32 + h * 8);
    }
}
__device__ __forceinline__ void wrlds_b(short* bt, int t, const short8* r) {
    #pragma unroll
    for (int rr = 0; rr < 2; ++rr) {
        int c = t + rr * 256;
        int n = c >> 2, h = c & 3;
        *(short8*)(bt + n * BST + h * 8) = r[rr];
    }
}

// ---------------------------------------------------------------------------
// node_gemm: P[n] = x @ W1[0:128] (fp32 out, row-side L1-hot gather target)
//            rec.Q[n] = bf16(x @ W1[128:256]) (col-side random gather target)
// 64 rows/block, grid.y = 2 column halves.
// Block (0,0) also zeroes gstats (runs before edge_pass in stream order).
// ---------------------------------------------------------------------------
__global__ __launch_bounds__(NT, 2)
void node_gemm(const float* __restrict__ x,
               const unsigned short* __restrict__ wt,    // [256 c][128 k] layer slice
               float* __restrict__ P,
               unsigned short* __restrict__ rec,         // [NND][256] bf16: x | Q
               float* __restrict__ gstats)
{
    __shared__ short lxa[TE * XST];
    __shared__ short lbt[128 * BST];

    const int t = threadIdx.x;
    const int lane = t & 63, quad = lane >> 4, ln15 = lane & 15;
    const int wv = t >> 6, we = wv >> 1, wc = wv & 1;
    const int n0 = blockIdx.x * 64;
    const int ch = blockIdx.y;
    const unsigned short* wsrc = wt + (size_t)ch * 128 * 128;

    if (blockIdx.x == 0 && ch == 0) gstats[t] = 0.f;   // 256 floats

    {   // stage A tile: fp32 -> bf16 conversion, full 32-short chunk/thread
        int row = t >> 2, q = t & 3;
        int src = min(n0 + row, NND - 1);
        const float4* xp = (const float4*)(x + (size_t)src * NF) + q * 8;
        #pragma unroll
        for (int u = 0; u < 4; ++u) {
            float4 a = xp[2*u], b = xp[2*u+1];
            short8 s;
            s[0]=f2bf(a.x); s[1]=f2bf(a.y); s[2]=f2bf(a.z); s[3]=f2bf(a.w);
            s[4]=f2bf(b.x); s[5]=f2bf(b.y); s[6]=f2bf(b.z); s[7]=f2bf(b.w);
            *(short8*)(lxa + row * XST + q * 32 + u * 8) = s;
        }
    }

    float4v acc[2][4];
    #pragma unroll
    for (int a = 0; a < 2; ++a)
        #pragma unroll
        for (int b = 0; b < 4; ++b) { float4v z = {0.f,0.f,0.f,0.f}; acc[a][b] = z; }

    for (int ks = 0; ks < 4; ++ks) {
        __syncthreads();
        stage_b(wsrc, NF, ks, lbt, t);
        __syncthreads();
        short8 af[2], bfr[4];
        #pragma unroll
        for (int ef = 0; ef < 2; ++ef)
            af[ef] = *(const short8*)(lxa + (we*32 + ef*16 + ln15) * XST + ks*32 + quad*8);
        #pragma unroll
        for (int fc = 0; fc < 4; ++fc)
            bfr[fc] = *(const short8*)(lbt + (wc*64 + fc*16 + ln15) * BST + quad*8);
        #pragma unroll
        for (int ef = 0; ef < 2; ++ef)
            #pragma unroll
            for (int fc = 0; fc < 4; ++fc)
                acc[ef][fc] = __builtin_amdgcn_mfma_f32_16x16x32_bf16(af[ef], bfr[fc], acc[ef][fc], 0, 0, 0);
    }
    #pragma unroll
    for (int fc = 0; fc < 4; ++fc) {
        int c = wc * 64 + fc * 16 + ln15;
        #pragma unroll
        for (int ef = 0; ef < 2; ++ef)
            #pragma unroll
            for (int rg = 0; rg < 4; ++rg) {
                int nrow = n0 + we * 32 + ef * 16 + quad * 4 + rg;
                if (nrow < NND) {
                    if (ch == 0)
                        P[(size_t)nrow * NF + c] = acc[ef][fc][rg];
                    else
                        rec[(size_t)nrow * 256 + 128 + c] =
                            (unsigned short)f2bf(acc[ef][fc][rg]);
                }
            }
    }
}

// pack_x: rec.x[n] = bf16(x[n]) for layer 0 (layers 1,2 fused into aggregate_k)
__global__ __launch_bounds__(NT)
void pack_x(const float* __restrict__ x, unsigned short* __restrict__ rec)
{
    int i = blockIdx.x * NT + threadIdx.x;   // one thread per 8 channels
    if (i >= NND * 16) return;
    int n = i >> 4, q = i & 15;
    const float4* xp = (const float4*)(x + (size_t)n * NF + q * 8);
    float4 a = xp[0], b = xp[1];
    short8 s;
    s[0]=f2bf(a.x); s[1]=f2bf(a.y); s[2]=f2bf(a.z); s[3]=f2bf(a.w);
    s[4]=f2bf(b.x); s[5]=f2bf(b.y); s[6]=f2bf(b.z); s[7]=f2bf(b.w);
    *(short8*)(rec + (size_t)n * 256 + q * 8) = s;
}

// ---------------------------------------------------------------------------
// edge_pass v8 (r11/r13-verified, 57us): 2-deep A/B pipeline, DPP reduce,
// fast psif, bounds(256,3). Grid swept to 1024 this round (was 768).
// PIPELINE-DEPTH WARNING (r12): 3-deep does NOT allocate more VGPRs — the
// compiler holds 84 (defending 6 waves/SIMD) and SPILLS the third ED state:
// WRITE 81->201MB, FETCH 105->197MB, dur 58->108us. VGPR_Count is NOT the
// tell; the traffic counters are. 2-deep/84-VGPR is the codegen optimum.
// CODEGEN WARNING (r4-r6): bounds(NT,4) caps VGPR 128 -> spill -> 5x traffic.
// ---------------------------------------------------------------------------
struct ED { float4 xi0, xi1, pr0, pr1, ea; short8 xj, qj; };

__device__ __forceinline__ void issue_edge(const float* __restrict__ x,
                                           const float* __restrict__ P,
                                           const unsigned short* __restrict__ rec,
                                           const float* __restrict__ eaS,
                                           int e, int2 rc, int c0, ED& d)
{
    const float4* xip = (const float4*)(x + (size_t)rc.x * NF + c0);
    const float4* prp = (const float4*)(P + (size_t)rc.x * NF + c0);
    const short8* rj  = (const short8*)(rec + (size_t)rc.y * 256 + c0);
    d.xi0 = xip[0]; d.xi1 = xip[1];
    d.pr0 = prp[0]; d.pr1 = prp[1];
    d.xj  = rj[0];  d.qj  = rj[16];        // +128 shorts = +16 short8
    d.ea  = ((const float4*)eaS)[e];
}

__device__ __forceinline__ void compute_edge(const ED& d, int e, int ln15, int c0,
                                             const float (&w6)[6][8],
                                             float (&ss)[8], float (&sq)[8],
                                             unsigned short* __restrict__ hpre)
{
    float xiv[8] = {d.xi0.x, d.xi0.y, d.xi0.z, d.xi0.w,
                    d.xi1.x, d.xi1.y, d.xi1.z, d.xi1.w};
    float nrm = 0.f, dot = 0.f;
    #pragma unroll
    for (int i = 0; i < 8; ++i) {
        float xj = bf2f(d.xj[i]);
        float dd = xiv[i] - xj;
        nrm = fmaf(-dd, dd, nrm);
        dot = fmaf(-xiv[i], xj, dot);
    }
    if (ln15 == 0) {   // metric fix: component 0 carries +, not -
        float xj0 = bf2f(d.xj[0]);
        float d0 = xiv[0] - xj0;
        nrm += 2.f * d0 * d0;
        dot += 2.f * xiv[0] * xj0;
    }
    nrm = rowsum16(nrm);   // DPP row_ror reduce: all 16 lanes get full sum
    dot = rowsum16(dot);
    const float pn = psif(nrm), pd = psif(dot);

    float prv[8] = {d.pr0.x, d.pr0.y, d.pr0.z, d.pr0.w,
                    d.pr1.x, d.pr1.y, d.pr1.z, d.pr1.w};
    short8 o;
    #pragma unroll
    for (int i = 0; i < 8; ++i) {
        float v = prv[i] + bf2f(d.qj[i]);
        v = fmaf(d.ea.x, w6[0][i], v);
        v = fmaf(d.ea.y, w6[1][i], v);
        v = fmaf(d.ea.z, w6[2][i], v);
        v = fmaf(d.ea.w, w6[3][i], v);
        v = fmaf(pn,     w6[4][i], v);
        v = fmaf(pd,     w6[5][i], v);
        ss[i] += v;
        sq[i] = fmaf(v, v, sq[i]);
        o[i] = f2bf(v);
    }
    *(short8*)(hpre + (size_t)e * NF + c0) = o;   // 256 B/edge coalesced
}

__global__ __launch_bounds__(NT, 3)
void edge_pass(const float* __restrict__ x,
               const float* __restrict__ P,
               const unsigned short* __restrict__ rec,
               const int2* __restrict__ rcS,
               const float* __restrict__ eaS,
               const float* __restrict__ W1l,   // fp32 layer slice [262][128]
               unsigned short* __restrict__ hpre,
               float* __restrict__ gstats)
{
    __shared__ float sred[4][256];

    const int t = threadIdx.x;
    const int lane = t & 63;
    const int wv = t >> 6;
    const int gg = lane >> 4;         // edge sub-index within wave
    const int ln15 = lane & 15;
    const int c0 = ln15 * 8;          // this lane's 8 channels

    // W1ext rows 256..261 for this lane's channels (loop-invariant, fp32)
    float w6[6][8];
    #pragma unroll
    for (int k = 0; k < 6; ++k) {
        const float4* wp = (const float4*)(W1l + (size_t)(256 + k) * NF + c0);
        float4 a = wp[0], b = wp[1];
        w6[k][0] = a.x; w6[k][1] = a.y; w6[k][2] = a.z; w6[k][3] = a.w;
        w6[k][4] = b.x; w6[k][5] = b.y; w6[k][6] = b.z; w6[k][7] = b.w;
    }

    float ss[8], sq[8];
    #pragma unroll
    for (int i = 0; i < 8; ++i) { ss[i] = 0.f; sq[i] = 0.f; }

    const int wid = blockIdx.x * 4 + wv;
    const int nw  = gridDim.x * 4;
    const int s2  = 2 * nw;

    ED A, B;
    int2 rcA = {0, 0}, rcB = {0, 0}, rcA2 = {0, 0}, rcB2 = {0, 0};
    int gA = wid, gB = wid + nw;

    // prologue: A-data in flight, B-indices in flight
    if (gA < NGRP) {
        rcA = rcS[gA * 4 + gg];
        issue_edge(x, P, rec, eaS, gA * 4 + gg, rcA, c0, A);
    }
    if (gB < NGRP) rcB = rcS[gB * 4 + gg];

    while (gA < NGRP) {
        if (gB < NGRP)
            issue_edge(x, P, rec, eaS, gB * 4 + gg, rcB, c0, B);   // B gathers fly under compute A
        int gA2 = gA + s2;
        if (gA2 < NGRP) rcA2 = rcS[gA2 * 4 + gg];                  // idx 2 ahead
        compute_edge(A, gA * 4 + gg, ln15, c0, w6, ss, sq, hpre);
        gA = gA2;
        if (gA < NGRP) {
            rcA = rcA2;
            issue_edge(x, P, rec, eaS, gA * 4 + gg, rcA, c0, A);   // A gathers fly under compute B
        }
        int gB2 = gB + s2;
        if (gB2 < NGRP) rcB2 = rcS[gB2 * 4 + gg];
        if (gB < NGRP)
            compute_edge(B, gB * 4 + gg, ln15, c0, w6, ss, sq, hpre);
        gB = gB2; rcB = rcB2;
    }

    // stats: combine the 4 edge-groups (lanes sharing ln15), then cross-wave
    #pragma unroll
    for (int i = 0; i < 8; ++i) {
        ss[i] += __shfl_xor(ss[i], 16); ss[i] += __shfl_xor(ss[i], 32);
        sq[i] += __shfl_xor(sq[i], 16); sq[i] += __shfl_xor(sq[i], 32);
    }
    if (lane < 16) {
        #pragma unroll
        for (int i = 0; i < 8; ++i) {
            sred[wv][c0 + i]       = ss[i];
            sred[wv][128 + c0 + i] = sq[i];
        }
    }
    __syncthreads();
    atomicAdd(&gstats[t], sred[0][t] + sred[1][t] + sred[2][t] + sred[3][t]);
}

// ---------------------------------------------------------------------------
// passB v3: r8-verified v1 structure (LDS-dbuf B staging) + DPP rowsum16
// epilogue reduce. (r11/r13-verified: out of top-5, <57us; unchanged.)
// ---------------------------------------------------------------------------
__global__ __launch_bounds__(NT, 4)
void passB(const unsigned short* __restrict__ hpre,
           const float* __restrict__ gstats,
           const float* __restrict__ gamma,
           const float* __restrict__ beta,
           const unsigned short* __restrict__ wt2,
           const float* __restrict__ b2,
           const unsigned short* __restrict__ wta,
           const float* __restrict__ ba,
           const float* __restrict__ wb,
           const float* __restrict__ wm,
           const float* __restrict__ bm,
           float* __restrict__ sG)
{
    __shared__ short lxi[TE * XST];     // hid, then mij
    __shared__ short lbt0[128 * BST];
    __shared__ short lbt1[128 * BST];
    __shared__ float gpart[2][TE];
    __shared__ float spart[2][TE];
    __shared__ float wgt[TE];
    __shared__ float scs[NF], sfs[NF];

    const int t = threadIdx.x;
    const int lane = t & 63, quad = lane >> 4, ln15 = lane & 15;
    const int wv = t >> 6, we = wv >> 1, wc = wv & 1;
    const int e0 = blockIdx.x * TE;
    const float bmv = bm[0];

    if (t < NF) {   // fused bn_finalize
        float mu  = gstats[t] * (1.f / NE);
        float var = fmaxf(gstats[128 + t] * (1.f / NE) - mu * mu, 0.f);
        float inv = rsqrtf(var + EPS);
        float sc  = gamma[t] * inv;
        scs[t] = sc;
        sfs[t] = beta[t] - mu * sc;
    }
    __syncthreads();

    // load hpre tile, BN+ReLU, store bf16 hid into lxi
    {
        const int le = t >> 2, q = t & 3;
        const unsigned short* hp = hpre + (size_t)(e0 + le) * NF + q * 32;
        #pragma unroll
        for (int h = 0; h < 4; ++h) {
            short8 v = *(const short8*)(hp + h * 8);
            short o[8];
            #pragma unroll
            for (int i = 0; i < 8; ++i) {
                int chn = q * 32 + h * 8 + i;
                float f = fmaxf(fmaf(bf2f(v[i]), scs[chn], sfs[chn]), 0.f);
                o[i] = f2bf(f);
            }
            *(short8*)(lxi + le * XST + q * 32 + h * 8) = *(short8*)o;
        }
    }

    float4v acc[2][4];
    #pragma unroll
    for (int a = 0; a < 2; ++a)
        #pragma unroll
        for (int b = 0; b < 4; ++b) { float4v z = {0.f,0.f,0.f,0.f}; acc[a][b] = z; }

    // ---- GEMM1: mij_raw = relu(hid @ W2 + b2), double-buffered B ----
    {
        short8 pre[2];
        ldreg_b(wt2, NF, 0, t, pre);
        wrlds_b(lbt0, t, pre);
        __syncthreads();   // covers hid writes too
        for (int ks = 0; ks < 4; ++ks) {
            short8 nxt[2];
            if (ks < 3) ldreg_b(wt2, NF, ks + 1, t, nxt);
            const short* cur = (ks & 1) ? lbt1 : lbt0;
            short8 af[2], bfr[4];
            #pragma unroll
            for (int ef = 0; ef < 2; ++ef)
                af[ef] = *(const short8*)(lxi + (we*32 + ef*16 + ln15) * XST + ks*32 + quad*8);
            #pragma unroll
            for (int fc = 0; fc < 4; ++fc)
                bfr[fc] = *(const short8*)(cur + (wc*64 + fc*16 + ln15) * BST + quad*8);
            #pragma unroll
            for (int ef = 0; ef < 2; ++ef)
                #pragma unroll
                for (int fc = 0; fc < 4; ++fc)
                    acc[ef][fc] = __builtin_amdgcn_mfma_f32_16x16x32_bf16(af[ef], bfr[fc], acc[ef][fc], 0, 0, 0);
            if (ks < 3) wrlds_b((ks & 1) ? lbt0 : lbt1, t, nxt);
            __syncthreads();
        }
    }

    // epilogue1: +b2, ReLU -> mij (bf16) back into lxi; gate partials with Wm
    {
        float p[2][4] = {{0.f,0.f,0.f,0.f},{0.f,0.f,0.f,0.f}};
        #pragma unroll
        for (int fc = 0; fc < 4; ++fc) {
            int c = wc * 64 + fc * 16 + ln15;
            float bb = b2[c], wmv = wm[c];
            #pragma unroll
            for (int ef = 0; ef < 2; ++ef)
                #pragma unroll
                for (int rg = 0; rg < 4; ++rg) {
                    int r = we * 32 + ef * 16 + quad * 4 + rg;
                    float v = fmaxf(acc[ef][fc][rg] + bb, 0.f);
                    lxi[r * XST + c] = f2bf(v);   // all GEMM1 lxi reads done (post-ks3 barrier)
                    p[ef][rg] = fmaf(v, wmv, p[ef][rg]);
                }
        }
        #pragma unroll
        for (int ef = 0; ef < 2; ++ef)
            #pragma unroll
            for (int rg = 0; rg < 4; ++rg)
                p[ef][rg] = rowsum16(p[ef][rg]);   // DPP reduce over ln15
        if (ln15 == 0) {
            #pragma unroll
            for (int ef = 0; ef < 2; ++ef)
                #pragma unroll
                for (int rg = 0; rg < 4; ++rg)
                    gpart[wc][we * 32 + ef * 16 + quad * 4 + rg] = p[ef][rg];
        }
    }

    // ---- GEMM2: relu(w * (mij @ Wa) + ba) . Wb ----
    #pragma unroll
    for (int a = 0; a < 2; ++a)
        #pragma unroll
        for (int b = 0; b < 4; ++b) { float4v z = {0.f,0.f,0.f,0.f}; acc[a][b] = z; }
    {
        short8 pre[2];
        ldreg_b(wta, NF, 0, t, pre);
        wrlds_b(lbt0, t, pre);      // lbt0 free (last read at GEMM1 ks=2 barrier)
        __syncthreads();            // covers gpart + mij writes + lbt0
        if (t < TE) wgt[t] = sigm(gpart[0][t] + gpart[1][t] + bmv);
        for (int ks = 0; ks < 4; ++ks) {
            short8 nxt[2];
            if (ks < 3) ldreg_b(wta, NF, ks + 1, t, nxt);
            const short* cur = (ks & 1) ? lbt1 : lbt0;
            short8 af[2], bfr[4];
            #pragma unroll
            for (int ef = 0; ef < 2; ++ef)
                af[ef] = *(const short8*)(lxi + (we*32 + ef*16 + ln15) * XST + ks*32 + quad*8);
            #pragma unroll
            for (int fc = 0; fc < 4; ++fc)
                bfr[fc] = *(const short8*)(cur + (wc*64 + fc*16 + ln15) * BST + quad*8);
            #pragma unroll
            for (int ef = 0; ef < 2; ++ef)
                #pragma unroll
                for (int fc = 0; fc < 4; ++fc)
                    acc[ef][fc] = __builtin_amdgcn_mfma_f32_16x16x32_bf16(af[ef], bfr[fc], acc[ef][fc], 0, 0, 0);
            if (ks < 3) wrlds_b((ks & 1) ? lbt0 : lbt1, t, nxt);
            __syncthreads();
        }
    }
    {
        float p[2][4] = {{0.f,0.f,0.f,0.f},{0.f,0.f,0.f,0.f}};
        #pragma unroll
        for (int fc = 0; fc < 4; ++fc) {
            int c = wc * 64 + fc * 16 + ln15;
            float bav = ba[c], wbv = wb[c];
            #pragma unroll
            for (int ef = 0; ef < 2; ++ef)
                #pragma unroll
                for (int rg = 0; rg < 4; ++rg) {
                    int r = we * 32 + ef * 16 + quad * 4 + rg;
                    float v = fmaxf(fmaf(wgt[r], acc[ef][fc][rg], bav), 0.f);
                    p[ef][rg] = fmaf(v, wbv, p[ef][rg]);
                }
        }
        #pragma unroll
        for (int ef = 0; ef < 2; ++ef)
            #pragma unroll
            for (int rg = 0; rg < 4; ++rg)
                p[ef][rg] = rowsum16(p[ef][rg]);
        if (ln15 == 0) {
            #pragma unroll
            for (int ef = 0; ef < 2; ++ef)
                #pragma unroll
                for (int rg = 0; rg < 4; ++rg)
                    spart[wc][we * 32 + ef * 16 + quad * 4 + rg] = p[ef][rg];
        }
    }
    __syncthreads();
    if (t < TE) sG[e0 + t] = spart[0][t] + spart[1][t];
}

// ---------------------------------------------------------------------------
// CSR build + edge reorder
// ---------------------------------------------------------------------------
__global__ __launch_bounds__(NT)
void hist_k(const int* __restrict__ ei, int* __restrict__ deg)
{
    int e = blockIdx.x * NT + threadIdx.x;
    if (e < NE) atomicAdd(&deg[ei[e]], 1);
}

__global__ __launch_bounds__(NT)
void scan_k(const int* __restrict__ deg, int* __restrict__ rowstart,
            int* __restrict__ cursor)
{
    __shared__ int part[NT];
    const int t = threadIdx.x;
    const int CH = (NND + NT - 1) / NT;
    const int base = t * CH;
    int sum = 0;
    for (int i = 0; i < CH; ++i) {
        int idx = base + i;
        if (idx < NND) sum += deg[idx];
    }
    part[t] = sum;
    __syncthreads();
    int pre = 0;
    for (int j = 0; j < t; ++j) pre += part[j];
    int run = pre;
    for (int i = 0; i < CH; ++i) {
        int idx = base + i;
        if (idx < NND) {
            rowstart[idx] = run;
            cursor[idx]   = run;
            run += deg[idx];
        }
    }
    if (t == NT - 1) rowstart[NND] = run;
}

__global__ __launch_bounds__(NT)
void fill_k(const int* __restrict__ ei, int* __restrict__ cursor,
            int* __restrict__ perm)
{
    int e = blockIdx.x * NT + threadIdx.x;
    if (e < NE) {
        int pos = atomicAdd(&cursor[ei[e]], 1);
        perm[pos] = e;
    }
}

__global__ __launch_bounds__(NT)
void prep_edges(const int* __restrict__ ei, const float* __restrict__ eattr,
                const int* __restrict__ perm,
                int2* __restrict__ rcS, int* __restrict__ colS,
                float* __restrict__ eaS)
{
    int p = blockIdx.x * NT + threadIdx.x;
    if (p >= NE) return;
    int e = perm[p];
    int r = ei[e];
    int c = ei[NE + e];
    rcS[p] = make_int2(r, c);
    colS[p] = c;
    ((float4*)eaS)[p] = ((const float4*)eattr)[e];
}

// ---------------------------------------------------------------------------
// Aggregation: one wave per node; 2-deep software pipeline on x[col] rows.
// Fuses the bf16 x-pack for the NEXT layer's edge_pass gather record.
// ---------------------------------------------------------------------------
__global__ __launch_bounds__(NT)
void aggregate_k(const float* __restrict__ x,
                 const float* __restrict__ sG,
                 const int* __restrict__ rowstart,
                 const int* __restrict__ colS,
                 float* __restrict__ xn,
                 unsigned short* __restrict__ rec)
{
    const int w  = (blockIdx.x * NT + threadIdx.x) >> 6;
    const int ln = threadIdx.x & 63;
    if (w >= NND) return;
    const int beg = rowstart[w], end = rowstart[w + 1];
    const float* xr = x + (size_t)w * NF;
    const float xr0 = xr[ln], xr1 = xr[ln + 64];
    float a0 = 0.f, a1 = 0.f;
    int p = beg;
    if (p < end) {
        int c = colS[p];
        float v0 = x[(size_t)c * NF + ln];
        float v1 = x[(size_t)c * NF + 64 + ln];
        for (; p + 1 < end; ++p) {
            int c2 = colS[p + 1];
            float w0 = x[(size_t)c2 * NF + ln];
            float w1 = x[(size_t)c2 * NF + 64 + ln];
            float s = sG[p];
            a0 += clipf((xr0 - v0) * s);
            a1 += clipf((xr1 - v1) * s);
            v0 = w0; v1 = w1;
        }
        float s = sG[p];
        a0 += clipf((xr0 - v0) * s);
        a1 += clipf((xr1 - v1) * s);
    }
    const float o0 = xr0 + a0;
    const float o1 = xr1 + a1;
    xn[(size_t)w * NF + ln]      = o0;
    xn[(size_t)w * NF + ln + 64] = o1;
    rec[(size_t)w * 256 + ln]      = (unsigned short)f2bf(o0);
    rec[(size_t)w * 256 + 64 + ln] = (unsigned short)f2bf(o1);
}

// Last layer: aggregate fused with final Linear+sigmoid
__global__ __launch_bounds__(NT)
void aggregate_final(const float* __restrict__ x,
                     const float* __restrict__ sG,
                     const int* __restrict__ rowstart,
                     const int* __restrict__ colS,
                     const float* __restrict__ We,
                     const float* __restrict__ be,
                     float* __restrict__ out)
{
    const int w  = (blockIdx.x * NT + threadIdx.x) >> 6;
    const int ln = threadIdx.x & 63;
    if (w >= NND) return;
    const int beg = rowstart[w], end = rowstart[w + 1];
    const float* xr = x + (size_t)w * NF;
    const float xr0 = xr[ln], xr1 = xr[ln + 64];
    float a0 = 0.f, a1 = 0.f;
    int p = beg;
    if (p < end) {
        int c = colS[p];
        float v0 = x[(size_t)c * NF + ln];
        float v1 = x[(size_t)c * NF + 64 + ln];
        for (; p + 1 < end; ++p) {
            int c2 = colS[p + 1];
            float w0 = x[(size_t)c2 * NF + ln];
            float w1 = x[(size_t)c2 * NF + 64 + ln];
            float s = sG[p];
            a0 += clipf((xr0 - v0) * s);
            a1 += clipf((xr1 - v1) * s);
            v0 = w0; v1 = w1;
        }
        float s = sG[p];
        a0 += clipf((xr0 - v0) * s);
        a1 += clipf((xr1 - v1) * s);
    }
    const float v0 = xr0 + a0;
    const float v1 = xr1 + a1;
    float o0 = v0 * We[ln * 2]     + v1 * We[(ln + 64) * 2];
    float o1 = v0 * We[ln * 2 + 1] + v1 * We[(ln + 64) * 2 + 1];
    #pragma unroll
    for (int m = 1; m < 64; m <<= 1) { o0 += __shfl_xor(o0, m); o1 += __shfl_xor(o1, m); }
    if (ln == 0) {
        out[w * 2]     = sigm(o0 + be[0]);
        out[w * 2 + 1] = sigm(o1 + be[1]);
    }
}

// ---------------------------------------------------------------------------
// Weight prep
// ---------------------------------------------------------------------------
// wt1n[l][c][k], c in 0..255: c<128 -> W1[l][k][c] (P half);
//                             c>=128 -> W1[l][128+k][c-128] (Q half)
__global__ __launch_bounds__(NT)
void prep_w1n(const float* __restrict__ W1, unsigned short* __restrict__ wt)
{
    int i = blockIdx.x * NT + threadIdx.x;
    if (i >= 3 * 256 * 128) return;
    int l = i / (256 * 128);
    int r = i % (256 * 128);
    int cc = r / 128, k = r % 128;
    int srow = (cc < 128) ? k : 128 + k;
    int scol = (cc < 128) ? cc : cc - 128;
    wt[i] = (unsigned short)f2bf(W1[((size_t)l * 262 + srow) * 128 + scol]);
}

__global__ __launch_bounds__(NT)
void prep_w128(const float* __restrict__ W, unsigned short* __restrict__ wt)
{
    int i = blockIdx.x * NT + threadIdx.x;
    if (i >= 3 * 128 * 128) return;
    int l = i / (128 * 128);
    int r = i % (128 * 128);
    int n = r / 128, k = r % 128;
    wt[i] = (unsigned short)f2bf(W[((size_t)l * 128 + k) * 128 + n]);
}

// ---------------------------------------------------------------------------
extern "C" void kernel_launch(void* const* d_in, const int* in_sizes, int n_in,
                              void* d_out, int out_size, void* d_ws, size_t ws_size,
                              hipStream_t stream) {
    const float* x   = (const float*)d_in[0];
    const int*   ei  = (const int*)d_in[1];
    const float* ea  = (const float*)d_in[2];
    const float* W1  = (const float*)d_in[3];
    const float* ga  = (const float*)d_in[4];
    const float* bet = (const float*)d_in[5];
    const float* W2  = (const float*)d_in[6];
    const float* b2  = (const float*)d_in[7];
    const float* Wa  = (const float*)d_in[8];
    const float* ba  = (const float*)d_in[9];
    const float* Wb  = (const float*)d_in[10];
    const float* Wm  = (const float*)d_in[11];
    const float* bm  = (const float*)d_in[12];
    const float* We  = (const float*)d_in[13];
    const float* be  = (const float*)d_in[14];
    float* out = (float*)d_out;

    // bump allocator over d_ws, 32B-aligned
    char* base = (char*)d_ws;
    size_t off = 0;
    auto alloc = [&](size_t bytes) -> void* {
        off = (off + 31) & ~(size_t)31;
        void* p = base + off;
        off += bytes;
        return p;
    };
    float* gstats   = (float*)alloc(256 * sizeof(float));
    int*   deg      = (int*)alloc(NND * sizeof(int));
    int*   rowstart = (int*)alloc((NND + 1) * sizeof(int));
    int*   cursor   = (int*)alloc(NND * sizeof(int));
    int*   perm     = (int*)alloc(NE * sizeof(int));
    int2*  rcS      = (int2*)alloc((size_t)NE * sizeof(int2));
    int*   colS     = (int*)alloc(NE * sizeof(int));
    float* eaS      = (float*)alloc((size_t)NE * 4 * sizeof(float));
    float* sG       = (float*)alloc(NE * sizeof(float));
    float* xA       = (float*)alloc((size_t)NND * NF * sizeof(float));
    float* xB       = (float*)alloc((size_t)NND * NF * sizeof(float));
    float* P        = (float*)alloc((size_t)NND * NF * sizeof(float));
    unsigned short* rec  = (unsigned short*)alloc((size_t)NND * 256 * 2);
    unsigned short* wt1n = (unsigned short*)alloc((size_t)3 * 256 * 128 * 2);
    unsigned short* wt2  = (unsigned short*)alloc((size_t)3 * 128 * 128 * 2);
    unsigned short* wta  = (unsigned short*)alloc((size_t)3 * 128 * 128 * 2);
    unsigned short* hpreG= (unsigned short*)alloc((size_t)NE * NF * 2);

    prep_w1n <<<(3 * 256 * 128 + NT - 1) / NT, NT, 0, stream>>>(W1, wt1n);
    prep_w128<<<(3 * 128 * 128 + NT - 1) / NT, NT, 0, stream>>>(W2, wt2);
    prep_w128<<<(3 * 128 * 128 + NT - 1) / NT, NT, 0, stream>>>(Wa, wta);

    hipMemsetAsync(deg, 0, NND * sizeof(int), stream);
    hist_k<<<(NE + NT - 1) / NT, NT, 0, stream>>>(ei, deg);
    scan_k<<<1, NT, 0, stream>>>(deg, rowstart, cursor);
    fill_k<<<(NE + NT - 1) / NT, NT, 0, stream>>>(ei, cursor, perm);
    prep_edges<<<(NE + NT - 1) / NT, NT, 0, stream>>>(ei, ea, perm, rcS, colS, eaS);
    pack_x<<<(NND * 16 + NT - 1) / NT, NT, 0, stream>>>(x, rec);

    const float* xc = x;
    float* buf[2] = { xA, xB };

    for (int l = 0; l < 3; ++l) {
        node_gemm<<<dim3((NND + 63) / 64, 2), NT, 0, stream>>>(
            xc, wt1n + (size_t)l * 256 * 128, P, rec, gstats);
        edge_pass<<<EGRID, NT, 0, stream>>>(xc, P, rec, rcS, eaS,
                                            W1 + (size_t)l * 262 * 128, hpreG, gstats);
        passB<<<NTILES, NT, 0, stream>>>(hpreG, gstats, ga + l * NF, bet + l * NF,
                                         wt2 + (size_t)l * 128 * 128, b2 + l * NF,
                                         wta + (size_t)l * 128 * 128, ba + l * NF,
                                         Wb + l * NF, Wm + l * NF, bm + l, sG);
        if (l < 2) {
            float* xn = buf[l & 1];
            aggregate_k<<<(NND * 64 + NT - 1) / NT, NT, 0, stream>>>(xc, sG, rowstart,
                                                                     colS, xn, rec);
            xc = xn;
        } else {
            aggregate_final<<<(NND * 64 + NT - 1) / NT, NT, 0, stream>>>(xc, sG, rowstart,
                                                                         colS, We, be, out);
        }
    }
}

// Round 16
// 628.220 us; speedup vs baseline: 1.0370x; 1.0370x over previous
//
#include <hip/hip_runtime.h>
#include <math.h>

#define NND 20000
#define NE  320000
#define NF  128
#define EPS 1e-5f
#define TE  64             // edges per tile (passB)
#define NT  256
#define NTILES (NE / TE)   // 5000
#define NGRP (NE / 4)      // 80000 edge groups of 4 (edge_pass)
#define EGRID 768          // FINAL: grid sweep complete {768:57.3us, 1024:64.0,
                           // 1536:93}. 768 = 3 blocks/CU is the measured optimum
                           // (sliding-window locality degrades at higher residency).
#define XST 136            // LDS stride for 128-wide bf16 tiles (shorts)
#define BST 40             // LDS stride for B slab rows (shorts)

typedef short short8 __attribute__((ext_vector_type(8)));
typedef float float4v __attribute__((ext_vector_type(4)));

__device__ __forceinline__ float psif(float z) {
    // sign(z)*log1p(|z|); __logf(1+|z|) error <=1e-5 through w6 (budget 3.9e-3)
    return copysignf(__logf(1.f + fabsf(z)), z);
}
__device__ __forceinline__ float sigm(float z) {
    return 1.f / (1.f + expf(-z));
}
__device__ __forceinline__ short f2bf(float f) {
    union { float f; unsigned u; } v; v.f = f;
    unsigned r = v.u + 0x7fffu + ((v.u >> 16) & 1u);
    return (short)(r >> 16);
}
__device__ __forceinline__ float bf2f(short u) {
    union { unsigned u; float f; } v; v.u = ((unsigned)(unsigned short)u) << 16;
    return v.f;
}
__device__ __forceinline__ float clipf(float v) {
    return fminf(fmaxf(v, -100.f), 100.f);
}

// rotate-reduce within each 16-lane DPP row: after steps 1,2,4,8 every lane
// holds the row sum. VALU-pipe (no ds_swizzle / lgkmcnt serial chain).
template<int N>
__device__ __forceinline__ float ror16_add(float v) {
    int r = __builtin_amdgcn_update_dpp(
        0, __float_as_int(v), 0x120 + N /*row_ror:N*/, 0xF, 0xF, false);
    return v + __int_as_float(r);
}
__device__ __forceinline__ float rowsum16(float v) {
    v = ror16_add<1>(v);
    v = ror16_add<2>(v);
    v = ror16_add<4>(v);
    v = ror16_add<8>(v);
    return v;
}

// stage one K=32 slab of Wt [128 rows n][wstride k] (bf16) into LDS bt[128][BST]
__device__ __forceinline__ void stage_b(const unsigned short* __restrict__ wsrc, int wstride,
                                        int ks, short* bt, int t) {
    #pragma unroll
    for (int rr = 0; rr < 2; ++rr) {
        int c = t + rr * 256;          // 512 chunks of 8 bf16
        int n = c >> 2, h = c & 3;
        short8 v = *(const short8*)(wsrc + (size_t)n * wstride + ks * 32 + h * 8);
        *(short8*)(bt + n * BST + h * 8) = v;
    }
}

// B-slab staging split for double-buffered loops (passB).
// NOTE (r10 lesson): do NOT replace LDS-dbuf B staging with per-wave global
// fragment loads — in-loop VMEM latency + same-line L2 contention made passB
// 64 -> 89.6us despite higher occupancy and fewer bank conflicts.
__device__ __forceinline__ void ldreg_b(const unsigned short* __restrict__ w, int wstride,
                                        int ks, int t, short8* r) {
    #pragma unroll
    for (int rr = 0; rr < 2; ++rr) {
        int c = t + rr * 256;
        int n = c >> 2, h = c & 3;
        r[rr] = *(const short8*)(w + (size_t)n * wstride + ks * 32 + h * 8);
    }
}
__device__ __forceinline__ void wrlds_b(short* bt, int t, const short8* r) {
    #pragma unroll
    for (int rr = 0; rr < 2; ++rr) {
        int c = t + rr * 256;
        int n = c >> 2, h = c & 3;
        *(short8*)(bt + n * BST + h * 8) = r[rr];
    }
}

// ---------------------------------------------------------------------------
// node_gemm: P[n] = x @ W1[0:128] (fp32 out, row-side L1-hot gather target)
//            rec.Q[n] = bf16(x @ W1[128:256]) (col-side random gather target)
// 64 rows/block, grid.y = 2 column halves.
// Block (0,0) also zeroes gstats (runs before edge_pass in stream order).
// ---------------------------------------------------------------------------
__global__ __launch_bounds__(NT, 2)
void node_gemm(const float* __restrict__ x,
               const unsigned short* __restrict__ wt,    // [256 c][128 k] layer slice
               float* __restrict__ P,
               unsigned short* __restrict__ rec,         // [NND][256] bf16: x | Q
               float* __restrict__ gstats)
{
    __shared__ short lxa[TE * XST];
    __shared__ short lbt[128 * BST];

    const int t = threadIdx.x;
    const int lane = t & 63, quad = lane >> 4, ln15 = lane & 15;
    const int wv = t >> 6, we = wv >> 1, wc = wv & 1;
    const int n0 = blockIdx.x * 64;
    const int ch = blockIdx.y;
    const unsigned short* wsrc = wt + (size_t)ch * 128 * 128;

    if (blockIdx.x == 0 && ch == 0) gstats[t] = 0.f;   // 256 floats

    {   // stage A tile: fp32 -> bf16 conversion, full 32-short chunk/thread
        int row = t >> 2, q = t & 3;
        int src = min(n0 + row, NND - 1);
        const float4* xp = (const float4*)(x + (size_t)src * NF) + q * 8;
        #pragma unroll
        for (int u = 0; u < 4; ++u) {
            float4 a = xp[2*u], b = xp[2*u+1];
            short8 s;
            s[0]=f2bf(a.x); s[1]=f2bf(a.y); s[2]=f2bf(a.z); s[3]=f2bf(a.w);
            s[4]=f2bf(b.x); s[5]=f2bf(b.y); s[6]=f2bf(b.z); s[7]=f2bf(b.w);
            *(short8*)(lxa + row * XST + q * 32 + u * 8) = s;
        }
    }

    float4v acc[2][4];
    #pragma unroll
    for (int a = 0; a < 2; ++a)
        #pragma unroll
        for (int b = 0; b < 4; ++b) { float4v z = {0.f,0.f,0.f,0.f}; acc[a][b] = z; }

    for (int ks = 0; ks < 4; ++ks) {
        __syncthreads();
        stage_b(wsrc, NF, ks, lbt, t);
        __syncthreads();
        short8 af[2], bfr[4];
        #pragma unroll
        for (int ef = 0; ef < 2; ++ef)
            af[ef] = *(const short8*)(lxa + (we*32 + ef*16 + ln15) * XST + ks*32 + quad*8);
        #pragma unroll
        for (int fc = 0; fc < 4; ++fc)
            bfr[fc] = *(const short8*)(lbt + (wc*64 + fc*16 + ln15) * BST + quad*8);
        #pragma unroll
        for (int ef = 0; ef < 2; ++ef)
            #pragma unroll
            for (int fc = 0; fc < 4; ++fc)
                acc[ef][fc] = __builtin_amdgcn_mfma_f32_16x16x32_bf16(af[ef], bfr[fc], acc[ef][fc], 0, 0, 0);
    }
    #pragma unroll
    for (int fc = 0; fc < 4; ++fc) {
        int c = wc * 64 + fc * 16 + ln15;
        #pragma unroll
        for (int ef = 0; ef < 2; ++ef)
            #pragma unroll
            for (int rg = 0; rg < 4; ++rg) {
                int nrow = n0 + we * 32 + ef * 16 + quad * 4 + rg;
                if (nrow < NND) {
                    if (ch == 0)
                        P[(size_t)nrow * NF + c] = acc[ef][fc][rg];
                    else
                        rec[(size_t)nrow * 256 + 128 + c] =
                            (unsigned short)f2bf(acc[ef][fc][rg]);
                }
            }
    }
}

// pack_x: rec.x[n] = bf16(x[n]) for layer 0 (layers 1,2 fused into aggregate_k)
__global__ __launch_bounds__(NT)
void pack_x(const float* __restrict__ x, unsigned short* __restrict__ rec)
{
    int i = blockIdx.x * NT + threadIdx.x;   // one thread per 8 channels
    if (i >= NND * 16) return;
    int n = i >> 4, q = i & 15;
    const float4* xp = (const float4*)(x + (size_t)n * NF + q * 8);
    float4 a = xp[0], b = xp[1];
    short8 s;
    s[0]=f2bf(a.x); s[1]=f2bf(a.y); s[2]=f2bf(a.z); s[3]=f2bf(a.w);
    s[4]=f2bf(b.x); s[5]=f2bf(b.y); s[6]=f2bf(b.z); s[7]=f2bf(b.w);
    *(short8*)(rec + (size_t)n * 256 + q * 8) = s;
}

// ---------------------------------------------------------------------------
// edge_pass v8 (r11/r13-verified, 57us @ EGRID 768): 2-deep A/B pipeline,
// DPP rotate-reduce, fast psif, bounds(256,3).
// PIPELINE-DEPTH WARNING (r12): 3-deep does NOT allocate more VGPRs — the
// compiler holds 84 (defending 6 waves/SIMD) and SPILLS the third ED state:
// WRITE 81->201MB, FETCH 105->197MB, dur 58->108us. VGPR_Count is NOT the
// tell; the traffic counters are. 2-deep/84-VGPR is the codegen optimum.
// CODEGEN WARNING (r4-r6): bounds(NT,4) caps VGPR 128 -> spill -> 5x traffic.
// GRID WARNING (r7/r14): sweep complete, 768 optimal (1024:+12%, 1536:+62%).
// ---------------------------------------------------------------------------
struct ED { float4 xi0, xi1, pr0, pr1, ea; short8 xj, qj; };

__device__ __forceinline__ void issue_edge(const float* __restrict__ x,
                                           const float* __restrict__ P,
                                           const unsigned short* __restrict__ rec,
                                           const float* __restrict__ eaS,
                                           int e, int2 rc, int c0, ED& d)
{
    const float4* xip = (const float4*)(x + (size_t)rc.x * NF + c0);
    const float4* prp = (const float4*)(P + (size_t)rc.x * NF + c0);
    const short8* rj  = (const short8*)(rec + (size_t)rc.y * 256 + c0);
    d.xi0 = xip[0]; d.xi1 = xip[1];
    d.pr0 = prp[0]; d.pr1 = prp[1];
    d.xj  = rj[0];  d.qj  = rj[16];        // +128 shorts = +16 short8
    d.ea  = ((const float4*)eaS)[e];
}

__device__ __forceinline__ void compute_edge(const ED& d, int e, int ln15, int c0,
                                             const float (&w6)[6][8],
                                             float (&ss)[8], float (&sq)[8],
                                             unsigned short* __restrict__ hpre)
{
    float xiv[8] = {d.xi0.x, d.xi0.y, d.xi0.z, d.xi0.w,
                    d.xi1.x, d.xi1.y, d.xi1.z, d.xi1.w};
    float nrm = 0.f, dot = 0.f;
    #pragma unroll
    for (int i = 0; i < 8; ++i) {
        float xj = bf2f(d.xj[i]);
        float dd = xiv[i] - xj;
        nrm = fmaf(-dd, dd, nrm);
        dot = fmaf(-xiv[i], xj, dot);
    }
    if (ln15 == 0) {   // metric fix: component 0 carries +, not -
        float xj0 = bf2f(d.xj[0]);
        float d0 = xiv[0] - xj0;
        nrm += 2.f * d0 * d0;
        dot += 2.f * xiv[0] * xj0;
    }
    nrm = rowsum16(nrm);   // DPP row_ror reduce: all 16 lanes get full sum
    dot = rowsum16(dot);
    const float pn = psif(nrm), pd = psif(dot);

    float prv[8] = {d.pr0.x, d.pr0.y, d.pr0.z, d.pr0.w,
                    d.pr1.x, d.pr1.y, d.pr1.z, d.pr1.w};
    short8 o;
    #pragma unroll
    for (int i = 0; i < 8; ++i) {
        float v = prv[i] + bf2f(d.qj[i]);
        v = fmaf(d.ea.x, w6[0][i], v);
        v = fmaf(d.ea.y, w6[1][i], v);
        v = fmaf(d.ea.z, w6[2][i], v);
        v = fmaf(d.ea.w, w6[3][i], v);
        v = fmaf(pn,     w6[4][i], v);
        v = fmaf(pd,     w6[5][i], v);
        ss[i] += v;
        sq[i] = fmaf(v, v, sq[i]);
        o[i] = f2bf(v);
    }
    *(short8*)(hpre + (size_t)e * NF + c0) = o;   // 256 B/edge coalesced
}

__global__ __launch_bounds__(NT, 3)
void edge_pass(const float* __restrict__ x,
               const float* __restrict__ P,
               const unsigned short* __restrict__ rec,
               const int2* __restrict__ rcS,
               const float* __restrict__ eaS,
               const float* __restrict__ W1l,   // fp32 layer slice [262][128]
               unsigned short* __restrict__ hpre,
               float* __restrict__ gstats)
{
    __shared__ float sred[4][256];

    const int t = threadIdx.x;
    const int lane = t & 63;
    const int wv = t >> 6;
    const int gg = lane >> 4;         // edge sub-index within wave
    const int ln15 = lane & 15;
    const int c0 = ln15 * 8;          // this lane's 8 channels

    // W1ext rows 256..261 for this lane's channels (loop-invariant, fp32)
    float w6[6][8];
    #pragma unroll
    for (int k = 0; k < 6; ++k) {
        const float4* wp = (const float4*)(W1l + (size_t)(256 + k) * NF + c0);
        float4 a = wp[0], b = wp[1];
        w6[k][0] = a.x; w6[k][1] = a.y; w6[k][2] = a.z; w6[k][3] = a.w;
        w6[k][4] = b.x; w6[k][5] = b.y; w6[k][6] = b.z; w6[k][7] = b.w;
    }

    float ss[8], sq[8];
    #pragma unroll
    for (int i = 0; i < 8; ++i) { ss[i] = 0.f; sq[i] = 0.f; }

    const int wid = blockIdx.x * 4 + wv;
    const int nw  = gridDim.x * 4;
    const int s2  = 2 * nw;

    ED A, B;
    int2 rcA = {0, 0}, rcB = {0, 0}, rcA2 = {0, 0}, rcB2 = {0, 0};
    int gA = wid, gB = wid + nw;

    // prologue: A-data in flight, B-indices in flight
    if (gA < NGRP) {
        rcA = rcS[gA * 4 + gg];
        issue_edge(x, P, rec, eaS, gA * 4 + gg, rcA, c0, A);
    }
    if (gB < NGRP) rcB = rcS[gB * 4 + gg];

    while (gA < NGRP) {
        if (gB < NGRP)
            issue_edge(x, P, rec, eaS, gB * 4 + gg, rcB, c0, B);   // B gathers fly under compute A
        int gA2 = gA + s2;
        if (gA2 < NGRP) rcA2 = rcS[gA2 * 4 + gg];                  // idx 2 ahead
        compute_edge(A, gA * 4 + gg, ln15, c0, w6, ss, sq, hpre);
        gA = gA2;
        if (gA < NGRP) {
            rcA = rcA2;
            issue_edge(x, P, rec, eaS, gA * 4 + gg, rcA, c0, A);   // A gathers fly under compute B
        }
        int gB2 = gB + s2;
        if (gB2 < NGRP) rcB2 = rcS[gB2 * 4 + gg];
        if (gB < NGRP)
            compute_edge(B, gB * 4 + gg, ln15, c0, w6, ss, sq, hpre);
        gB = gB2; rcB = rcB2;
    }

    // stats: combine the 4 edge-groups (lanes sharing ln15), then cross-wave
    #pragma unroll
    for (int i = 0; i < 8; ++i) {
        ss[i] += __shfl_xor(ss[i], 16); ss[i] += __shfl_xor(ss[i], 32);
        sq[i] += __shfl_xor(sq[i], 16); sq[i] += __shfl_xor(sq[i], 32);
    }
    if (lane < 16) {
        #pragma unroll
        for (int i = 0; i < 8; ++i) {
            sred[wv][c0 + i]       = ss[i];
            sred[wv][128 + c0 + i] = sq[i];
        }
    }
    __syncthreads();
    atomicAdd(&gstats[t], sred[0][t] + sred[1][t] + sred[2][t] + sred[3][t]);
}

// ---------------------------------------------------------------------------
// passB v3: r8-verified v1 structure (LDS-dbuf B staging) + DPP rowsum16
// epilogue reduce. (r11/r13-verified: out of top-5, <57us; unchanged.)
// ---------------------------------------------------------------------------
__global__ __launch_bounds__(NT, 4)
void passB(const unsigned short* __restrict__ hpre,
           const float* __restrict__ gstats,
           const float* __restrict__ gamma,
           const float* __restrict__ beta,
           const unsigned short* __restrict__ wt2,
           const float* __restrict__ b2,
           const unsigned short* __restrict__ wta,
           const float* __restrict__ ba,
           const float* __restrict__ wb,
           const float* __restrict__ wm,
           const float* __restrict__ bm,
           float* __restrict__ sG)
{
    __shared__ short lxi[TE * XST];     // hid, then mij
    __shared__ short lbt0[128 * BST];
    __shared__ short lbt1[128 * BST];
    __shared__ float gpart[2][TE];
    __shared__ float spart[2][TE];
    __shared__ float wgt[TE];
    __shared__ float scs[NF], sfs[NF];

    const int t = threadIdx.x;
    const int lane = t & 63, quad = lane >> 4, ln15 = lane & 15;
    const int wv = t >> 6, we = wv >> 1, wc = wv & 1;
    const int e0 = blockIdx.x * TE;
    const float bmv = bm[0];

    if (t < NF) {   // fused bn_finalize
        float mu  = gstats[t] * (1.f / NE);
        float var = fmaxf(gstats[128 + t] * (1.f / NE) - mu * mu, 0.f);
        float inv = rsqrtf(var + EPS);
        float sc  = gamma[t] * inv;
        scs[t] = sc;
        sfs[t] = beta[t] - mu * sc;
    }
    __syncthreads();

    // load hpre tile, BN+ReLU, store bf16 hid into lxi
    {
        const int le = t >> 2, q = t & 3;
        const unsigned short* hp = hpre + (size_t)(e0 + le) * NF + q * 32;
        #pragma unroll
        for (int h = 0; h < 4; ++h) {
            short8 v = *(const short8*)(hp + h * 8);
            short o[8];
            #pragma unroll
            for (int i = 0; i < 8; ++i) {
                int chn = q * 32 + h * 8 + i;
                float f = fmaxf(fmaf(bf2f(v[i]), scs[chn], sfs[chn]), 0.f);
                o[i] = f2bf(f);
            }
            *(short8*)(lxi + le * XST + q * 32 + h * 8) = *(short8*)o;
        }
    }

    float4v acc[2][4];
    #pragma unroll
    for (int a = 0; a < 2; ++a)
        #pragma unroll
        for (int b = 0; b < 4; ++b) { float4v z = {0.f,0.f,0.f,0.f}; acc[a][b] = z; }

    // ---- GEMM1: mij_raw = relu(hid @ W2 + b2), double-buffered B ----
    {
        short8 pre[2];
        ldreg_b(wt2, NF, 0, t, pre);
        wrlds_b(lbt0, t, pre);
        __syncthreads();   // covers hid writes too
        for (int ks = 0; ks < 4; ++ks) {
            short8 nxt[2];
            if (ks < 3) ldreg_b(wt2, NF, ks + 1, t, nxt);
            const short* cur = (ks & 1) ? lbt1 : lbt0;
            short8 af[2], bfr[4];
            #pragma unroll
            for (int ef = 0; ef < 2; ++ef)
                af[ef] = *(const short8*)(lxi + (we*32 + ef*16 + ln15) * XST + ks*32 + quad*8);
            #pragma unroll
            for (int fc = 0; fc < 4; ++fc)
                bfr[fc] = *(const short8*)(cur + (wc*64 + fc*16 + ln15) * BST + quad*8);
            #pragma unroll
            for (int ef = 0; ef < 2; ++ef)
                #pragma unroll
                for (int fc = 0; fc < 4; ++fc)
                    acc[ef][fc] = __builtin_amdgcn_mfma_f32_16x16x32_bf16(af[ef], bfr[fc], acc[ef][fc], 0, 0, 0);
            if (ks < 3) wrlds_b((ks & 1) ? lbt0 : lbt1, t, nxt);
            __syncthreads();
        }
    }

    // epilogue1: +b2, ReLU -> mij (bf16) back into lxi; gate partials with Wm
    {
        float p[2][4] = {{0.f,0.f,0.f,0.f},{0.f,0.f,0.f,0.f}};
        #pragma unroll
        for (int fc = 0; fc < 4; ++fc) {
            int c = wc * 64 + fc * 16 + ln15;
            float bb = b2[c], wmv = wm[c];
            #pragma unroll
            for (int ef = 0; ef < 2; ++ef)
                #pragma unroll
                for (int rg = 0; rg < 4; ++rg) {
                    int r = we * 32 + ef * 16 + quad * 4 + rg;
                    float v = fmaxf(acc[ef][fc][rg] + bb, 0.f);
                    lxi[r * XST + c] = f2bf(v);   // all GEMM1 lxi reads done (post-ks3 barrier)
                    p[ef][rg] = fmaf(v, wmv, p[ef][rg]);
                }
        }
        #pragma unroll
        for (int ef = 0; ef < 2; ++ef)
            #pragma unroll
            for (int rg = 0; rg < 4; ++rg)
                p[ef][rg] = rowsum16(p[ef][rg]);   // DPP reduce over ln15
        if (ln15 == 0) {
            #pragma unroll
            for (int ef = 0; ef < 2; ++ef)
                #pragma unroll
                for (int rg = 0; rg < 4; ++rg)
                    gpart[wc][we * 32 + ef * 16 + quad * 4 + rg] = p[ef][rg];
        }
    }

    // ---- GEMM2: relu(w * (mij @ Wa) + ba) . Wb ----
    #pragma unroll
    for (int a = 0; a < 2; ++a)
        #pragma unroll
        for (int b = 0; b < 4; ++b) { float4v z = {0.f,0.f,0.f,0.f}; acc[a][b] = z; }
    {
        short8 pre[2];
        ldreg_b(wta, NF, 0, t, pre);
        wrlds_b(lbt0, t, pre);      // lbt0 free (last read at GEMM1 ks=2 barrier)
        __syncthreads();            // covers gpart + mij writes + lbt0
        if (t < TE) wgt[t] = sigm(gpart[0][t] + gpart[1][t] + bmv);
        for (int ks = 0; ks < 4; ++ks) {
            short8 nxt[2];
            if (ks < 3) ldreg_b(wta, NF, ks + 1, t, nxt);
            const short* cur = (ks & 1) ? lbt1 : lbt0;
            short8 af[2], bfr[4];
            #pragma unroll
            for (int ef = 0; ef < 2; ++ef)
                af[ef] = *(const short8*)(lxi + (we*32 + ef*16 + ln15) * XST + ks*32 + quad*8);
            #pragma unroll
            for (int fc = 0; fc < 4; ++fc)
                bfr[fc] = *(const short8*)(cur + (wc*64 + fc*16 + ln15) * BST + quad*8);
            #pragma unroll
            for (int ef = 0; ef < 2; ++ef)
                #pragma unroll
                for (int fc = 0; fc < 4; ++fc)
                    acc[ef][fc] = __builtin_amdgcn_mfma_f32_16x16x32_bf16(af[ef], bfr[fc], acc[ef][fc], 0, 0, 0);
            if (ks < 3) wrlds_b((ks & 1) ? lbt0 : lbt1, t, nxt);
            __syncthreads();
        }
    }
    {
        float p[2][4] = {{0.f,0.f,0.f,0.f},{0.f,0.f,0.f,0.f}};
        #pragma unroll
        for (int fc = 0; fc < 4; ++fc) {
            int c = wc * 64 + fc * 16 + ln15;
            float bav = ba[c], wbv = wb[c];
            #pragma unroll
            for (int ef = 0; ef < 2; ++ef)
                #pragma unroll
                for (int rg = 0; rg < 4; ++rg) {
                    int r = we * 32 + ef * 16 + quad * 4 + rg;
                    float v = fmaxf(fmaf(wgt[r], acc[ef][fc][rg], bav), 0.f);
                    p[ef][rg] = fmaf(v, wbv, p[ef][rg]);
                }
        }
        #pragma unroll
        for (int ef = 0; ef < 2; ++ef)
            #pragma unroll
            for (int rg = 0; rg < 4; ++rg)
                p[ef][rg] = rowsum16(p[ef][rg]);
        if (ln15 == 0) {
            #pragma unroll
            for (int ef = 0; ef < 2; ++ef)
                #pragma unroll
                for (int rg = 0; rg < 4; ++rg)
                    spart[wc][we * 32 + ef * 16 + quad * 4 + rg] = p[ef][rg];
        }
    }
    __syncthreads();
    if (t < TE) sG[e0 + t] = spart[0][t] + spart[1][t];
}

// ---------------------------------------------------------------------------
// CSR build + edge reorder
// ---------------------------------------------------------------------------
__global__ __launch_bounds__(NT)
void hist_k(const int* __restrict__ ei, int* __restrict__ deg)
{
    int e = blockIdx.x * NT + threadIdx.x;
    if (e < NE) atomicAdd(&deg[ei[e]], 1);
}

__global__ __launch_bounds__(NT)
void scan_k(const int* __restrict__ deg, int* __restrict__ rowstart,
            int* __restrict__ cursor)
{
    __shared__ int part[NT];
    const int t = threadIdx.x;
    const int CH = (NND + NT - 1) / NT;
    const int base = t * CH;
    int sum = 0;
    for (int i = 0; i < CH; ++i) {
        int idx = base + i;
        if (idx < NND) sum += deg[idx];
    }
    part[t] = sum;
    __syncthreads();
    int pre = 0;
    for (int j = 0; j < t; ++j) pre += part[j];
    int run = pre;
    for (int i = 0; i < CH; ++i) {
        int idx = base + i;
        if (idx < NND) {
            rowstart[idx] = run;
            cursor[idx]   = run;
            run += deg[idx];
        }
    }
    if (t == NT - 1) rowstart[NND] = run;
}

__global__ __launch_bounds__(NT)
void fill_k(const int* __restrict__ ei, int* __restrict__ cursor,
            int* __restrict__ perm)
{
    int e = blockIdx.x * NT + threadIdx.x;
    if (e < NE) {
        int pos = atomicAdd(&cursor[ei[e]], 1);
        perm[pos] = e;
    }
}

__global__ __launch_bounds__(NT)
void prep_edges(const int* __restrict__ ei, const float* __restrict__ eattr,
                const int* __restrict__ perm,
                int2* __restrict__ rcS, int* __restrict__ colS,
                float* __restrict__ eaS)
{
    int p = blockIdx.x * NT + threadIdx.x;
    if (p >= NE) return;
    int e = perm[p];
    int r = ei[e];
    int c = ei[NE + e];
    rcS[p] = make_int2(r, c);
    colS[p] = c;
    ((float4*)eaS)[p] = ((const float4*)eattr)[e];
}

// ---------------------------------------------------------------------------
// Aggregation: one wave per node; 2-deep software pipeline on x[col] rows.
// Fuses the bf16 x-pack for the NEXT layer's edge_pass gather record.
// ---------------------------------------------------------------------------
__global__ __launch_bounds__(NT)
void aggregate_k(const float* __restrict__ x,
                 const float* __restrict__ sG,
                 const int* __restrict__ rowstart,
                 const int* __restrict__ colS,
                 float* __restrict__ xn,
                 unsigned short* __restrict__ rec)
{
    const int w  = (blockIdx.x * NT + threadIdx.x) >> 6;
    const int ln = threadIdx.x & 63;
    if (w >= NND) return;
    const int beg = rowstart[w], end = rowstart[w + 1];
    const float* xr = x + (size_t)w * NF;
    const float xr0 = xr[ln], xr1 = xr[ln + 64];
    float a0 = 0.f, a1 = 0.f;
    int p = beg;
    if (p < end) {
        int c = colS[p];
        float v0 = x[(size_t)c * NF + ln];
        float v1 = x[(size_t)c * NF + 64 + ln];
        for (; p + 1 < end; ++p) {
            int c2 = colS[p + 1];
            float w0 = x[(size_t)c2 * NF + ln];
            float w1 = x[(size_t)c2 * NF + 64 + ln];
            float s = sG[p];
            a0 += clipf((xr0 - v0) * s);
            a1 += clipf((xr1 - v1) * s);
            v0 = w0; v1 = w1;
        }
        float s = sG[p];
        a0 += clipf((xr0 - v0) * s);
        a1 += clipf((xr1 - v1) * s);
    }
    const float o0 = xr0 + a0;
    const float o1 = xr1 + a1;
    xn[(size_t)w * NF + ln]      = o0;
    xn[(size_t)w * NF + ln + 64] = o1;
    rec[(size_t)w * 256 + ln]      = (unsigned short)f2bf(o0);
    rec[(size_t)w * 256 + 64 + ln] = (unsigned short)f2bf(o1);
}

// Last layer: aggregate fused with final Linear+sigmoid
__global__ __launch_bounds__(NT)
void aggregate_final(const float* __restrict__ x,
                     const float* __restrict__ sG,
                     const int* __restrict__ rowstart,
                     const int* __restrict__ colS,
                     const float* __restrict__ We,
                     const float* __restrict__ be,
                     float* __restrict__ out)
{
    const int w  = (blockIdx.x * NT + threadIdx.x) >> 6;
    const int ln = threadIdx.x & 63;
    if (w >= NND) return;
    const int beg = rowstart[w], end = rowstart[w + 1];
    const float* xr = x + (size_t)w * NF;
    const float xr0 = xr[ln], xr1 = xr[ln + 64];
    float a0 = 0.f, a1 = 0.f;
    int p = beg;
    if (p < end) {
        int c = colS[p];
        float v0 = x[(size_t)c * NF + ln];
        float v1 = x[(size_t)c * NF + 64 + ln];
        for (; p + 1 < end; ++p) {
            int c2 = colS[p + 1];
            float w0 = x[(size_t)c2 * NF + ln];
            float w1 = x[(size_t)c2 * NF + 64 + ln];
            float s = sG[p];
            a0 += clipf((xr0 - v0) * s);
            a1 += clipf((xr1 - v1) * s);
            v0 = w0; v1 = w1;
        }
        float s = sG[p];
        a0 += clipf((xr0 - v0) * s);
        a1 += clipf((xr1 - v1) * s);
    }
    const float v0 = xr0 + a0;
    const float v1 = xr1 + a1;
    float o0 = v0 * We[ln * 2]     + v1 * We[(ln + 64) * 2];
    float o1 = v0 * We[ln * 2 + 1] + v1 * We[(ln + 64) * 2 + 1];
    #pragma unroll
    for (int m = 1; m < 64; m <<= 1) { o0 += __shfl_xor(o0, m); o1 += __shfl_xor(o1, m); }
    if (ln == 0) {
        out[w * 2]     = sigm(o0 + be[0]);
        out[w * 2 + 1] = sigm(o1 + be[1]);
    }
}

// ---------------------------------------------------------------------------
// Weight prep
// ---------------------------------------------------------------------------
// wt1n[l][c][k], c in 0..255: c<128 -> W1[l][k][c] (P half);
//                             c>=128 -> W1[l][128+k][c-128] (Q half)
__global__ __launch_bounds__(NT)
void prep_w1n(const float* __restrict__ W1, unsigned short* __restrict__ wt)
{
    int i = blockIdx.x * NT + threadIdx.x;
    if (i >= 3 * 256 * 128) return;
    int l = i / (256 * 128);
    int r = i % (256 * 128);
    int cc = r / 128, k = r % 128;
    int srow = (cc < 128) ? k : 128 + k;
    int scol = (cc < 128) ? cc : cc - 128;
    wt[i] = (unsigned short)f2bf(W1[((size_t)l * 262 + srow) * 128 + scol]);
}

__global__ __launch_bounds__(NT)
void prep_w128(const float* __restrict__ W, unsigned short* __restrict__ wt)
{
    int i = blockIdx.x * NT + threadIdx.x;
    if (i >= 3 * 128 * 128) return;
    int l = i / (128 * 128);
    int r = i % (128 * 128);
    int n = r / 128, k = r % 128;
    wt[i] = (unsigned short)f2bf(W[((size_t)l * 128 + k) * 128 + n]);
}

// ---------------------------------------------------------------------------
extern "C" void kernel_launch(void* const* d_in, const int* in_sizes, int n_in,
                              void* d_out, int out_size, void* d_ws, size_t ws_size,
                              hipStream_t stream) {
    const float* x   = (const float*)d_in[0];
    const int*   ei  = (const int*)d_in[1];
    const float* ea  = (const float*)d_in[2];
    const float* W1  = (const float*)d_in[3];
    const float* ga  = (const float*)d_in[4];
    const float* bet = (const float*)d_in[5];
    const float* W2  = (const float*)d_in[6];
    const float* b2  = (const float*)d_in[7];
    const float* Wa  = (const float*)d_in[8];
    const float* ba  = (const float*)d_in[9];
    const float* Wb  = (const float*)d_in[10];
    const float* Wm  = (const float*)d_in[11];
    const float* bm  = (const float*)d_in[12];
    const float* We  = (const float*)d_in[13];
    const float* be  = (const float*)d_in[14];
    float* out = (float*)d_out;

    // bump allocator over d_ws, 32B-aligned
    char* base = (char*)d_ws;
    size_t off = 0;
    auto alloc = [&](size_t bytes) -> void* {
        off = (off + 31) & ~(size_t)31;
        void* p = base + off;
        off += bytes;
        return p;
    };
    float* gstats   = (float*)alloc(256 * sizeof(float));
    int*   deg      = (int*)alloc(NND * sizeof(int));
    int*   rowstart = (int*)alloc((NND + 1) * sizeof(int));
    int*   cursor   = (int*)alloc(NND * sizeof(int));
    int*   perm     = (int*)alloc(NE * sizeof(int));
    int2*  rcS      = (int2*)alloc((size_t)NE * sizeof(int2));
    int*   colS     = (int*)alloc(NE * sizeof(int));
    float* eaS      = (float*)alloc((size_t)NE * 4 * sizeof(float));
    float* sG       = (float*)alloc(NE * sizeof(float));
    float* xA       = (float*)alloc((size_t)NND * NF * sizeof(float));
    float* xB       = (float*)alloc((size_t)NND * NF * sizeof(float));
    float* P        = (float*)alloc((size_t)NND * NF * sizeof(float));
    unsigned short* rec  = (unsigned short*)alloc((size_t)NND * 256 * 2);
    unsigned short* wt1n = (unsigned short*)alloc((size_t)3 * 256 * 128 * 2);
    unsigned short* wt2  = (unsigned short*)alloc((size_t)3 * 128 * 128 * 2);
    unsigned short* wta  = (unsigned short*)alloc((size_t)3 * 128 * 128 * 2);
    unsigned short* hpreG= (unsigned short*)alloc((size_t)NE * NF * 2);

    prep_w1n <<<(3 * 256 * 128 + NT - 1) / NT, NT, 0, stream>>>(W1, wt1n);
    prep_w128<<<(3 * 128 * 128 + NT - 1) / NT, NT, 0, stream>>>(W2, wt2);
    prep_w128<<<(3 * 128 * 128 + NT - 1) / NT, NT, 0, stream>>>(Wa, wta);

    hipMemsetAsync(deg, 0, NND * sizeof(int), stream);
    hist_k<<<(NE + NT - 1) / NT, NT, 0, stream>>>(ei, deg);
    scan_k<<<1, NT, 0, stream>>>(deg, rowstart, cursor);
    fill_k<<<(NE + NT - 1) / NT, NT, 0, stream>>>(ei, cursor, perm);
    prep_edges<<<(NE + NT - 1) / NT, NT, 0, stream>>>(ei, ea, perm, rcS, colS, eaS);
    pack_x<<<(NND * 16 + NT - 1) / NT, NT, 0, stream>>>(x, rec);

    const float* xc = x;
    float* buf[2] = { xA, xB };

    for (int l = 0; l < 3; ++l) {
        node_gemm<<<dim3((NND + 63) / 64, 2), NT, 0, stream>>>(
            xc, wt1n + (size_t)l * 256 * 128, P, rec, gstats);
        edge_pass<<<EGRID, NT, 0, stream>>>(xc, P, rec, rcS, eaS,
                                            W1 + (size_t)l * 262 * 128, hpreG, gstats);
        passB<<<NTILES, NT, 0, stream>>>(hpreG, gstats, ga + l * NF, bet + l * NF,
                                         wt2 + (size_t)l * 128 * 128, b2 + l * NF,
                                         wta + (size_t)l * 128 * 128, ba + l * NF,
                                         Wb + l * NF, Wm + l * NF, bm + l, sG);
        if (l < 2) {
            float* xn = buf[l & 1];
            aggregate_k<<<(NND * 64 + NT - 1) / NT, NT, 0, stream>>>(xc, sG, rowstart,
                                                                     colS, xn, rec);
            xc = xn;
        } else {
            aggregate_final<<<(NND * 64 + NT - 1) / NT, NT, 0, stream>>>(xc, sG, rowstart,
                                                                         colS, We, be, out);
        }
    }
}